// Round 1
// baseline (7523.985 us; speedup 1.0000x reference)
//
#include <hip/hip_runtime.h>

#define NN 200000
#define F_IN 128
#define HID 35
#define NCLS 10
#define LD1 36   // padded row stride for 35-wide (float4-aligned: 144B)
#define LD2 12   // padded row stride for 10-wide (48B)

__global__ void k_init_deg(float* __restrict__ deg, int n) {
    int i = blockIdx.x * blockDim.x + threadIdx.x;
    if (i < n) deg[i] = 1.0f;  // self loop
}

__global__ void k_count_deg(const int* __restrict__ col, int E, float* __restrict__ deg) {
    int e = blockIdx.x * blockDim.x + threadIdx.x;
    if (e < E) atomicAdd(&deg[col[e]], 1.0f);
}

__global__ void k_rsqrt(float* __restrict__ deg, int n) {
    int i = blockIdx.x * blockDim.x + threadIdx.x;
    if (i < n) deg[i] = rsqrtf(deg[i]);  // deg >= 1 always
}

// hs1[i][j] = dinv[i] * sum_k x[i][k] * W1[k][j]
__global__ void k_gemm1(const float* __restrict__ x, const float* __restrict__ W1,
                        const float* __restrict__ dinv, float* __restrict__ hs1, int n) {
    int i = blockIdx.x * blockDim.x + threadIdx.x;
    if (i >= n) return;
    float acc[HID];
#pragma unroll
    for (int j = 0; j < HID; ++j) acc[j] = 0.f;
    const float4* xr = (const float4*)(x + (size_t)i * F_IN);
    for (int k4 = 0; k4 < F_IN / 4; ++k4) {
        float4 xv = xr[k4];
        const float* w = W1 + (size_t)(k4 * 4) * HID;  // uniform index -> s_load
#pragma unroll
        for (int j = 0; j < HID; ++j)
            acc[j] += xv.x * w[j] + xv.y * w[HID + j] + xv.z * w[2 * HID + j] + xv.w * w[3 * HID + j];
    }
    float d = dinv[i];
    float* o = hs1 + (size_t)i * LD1;
#pragma unroll
    for (int j = 0; j < HID; ++j) o[j] = acc[j] * d;
    o[35] = 0.f;  // pad
}

// acc1[col] += hs1[row]  (self-loop already in acc1 via d2d init copy)
__global__ void k_scatter1(const int* __restrict__ row, const int* __restrict__ col, int E,
                           const float* __restrict__ hs1, float* __restrict__ acc1) {
    int e = blockIdx.x * blockDim.x + threadIdx.x;
    if (e >= E) return;
    int r = row[e], c = col[e];
    const float4* s = (const float4*)(hs1 + (size_t)r * LD1);
    float4 v[9];
#pragma unroll
    for (int q = 0; q < 9; ++q) v[q] = s[q];
    const float* vf = (const float*)v;
    float* dst = acc1 + (size_t)c * LD1;
#pragma unroll
    for (int f = 0; f < HID; ++f) atomicAdd(dst + f, vf[f]);
}

// h = relu(acc1*dinv + b1); hs2 = (h @ W2) * dinv
__global__ void k_layer2(const float* __restrict__ acc1, const float* __restrict__ dinv,
                         const float* __restrict__ b1, const float* __restrict__ W2,
                         float* __restrict__ hs2, int n) {
    int i = blockIdx.x * blockDim.x + threadIdx.x;
    if (i >= n) return;
    float d = dinv[i];
    const float4* a = (const float4*)(acc1 + (size_t)i * LD1);
    float4 t[9];
#pragma unroll
    for (int q = 0; q < 9; ++q) t[q] = a[q];
    const float* tf = (const float*)t;
    float h[HID];
#pragma unroll
    for (int k = 0; k < HID; ++k) {
        float v = tf[k] * d + b1[k];
        h[k] = v > 0.f ? v : 0.f;
    }
    float o[NCLS];
#pragma unroll
    for (int j = 0; j < NCLS; ++j) o[j] = 0.f;
#pragma unroll
    for (int k = 0; k < HID; ++k) {
#pragma unroll
        for (int j = 0; j < NCLS; ++j) o[j] += h[k] * W2[k * NCLS + j];
    }
    float* dst = hs2 + (size_t)i * LD2;
#pragma unroll
    for (int j = 0; j < NCLS; ++j) dst[j] = o[j] * d;
    dst[10] = 0.f;
    dst[11] = 0.f;
}

__global__ void k_scatter2(const int* __restrict__ row, const int* __restrict__ col, int E,
                           const float* __restrict__ hs2, float* __restrict__ acc2) {
    int e = blockIdx.x * blockDim.x + threadIdx.x;
    if (e >= E) return;
    int r = row[e], c = col[e];
    const float4* s = (const float4*)(hs2 + (size_t)r * LD2);
    float4 v0 = s[0], v1 = s[1], v2 = s[2];
    float* dst = acc2 + (size_t)c * LD2;
    atomicAdd(dst + 0, v0.x); atomicAdd(dst + 1, v0.y);
    atomicAdd(dst + 2, v0.z); atomicAdd(dst + 3, v0.w);
    atomicAdd(dst + 4, v1.x); atomicAdd(dst + 5, v1.y);
    atomicAdd(dst + 6, v1.z); atomicAdd(dst + 7, v1.w);
    atomicAdd(dst + 8, v2.x); atomicAdd(dst + 9, v2.y);
}

// out = log_softmax(acc2*dinv + b2)
__global__ void k_out(const float* __restrict__ acc2, const float* __restrict__ dinv,
                      const float* __restrict__ b2, float* __restrict__ out, int n) {
    int i = blockIdx.x * blockDim.x + threadIdx.x;
    if (i >= n) return;
    float d = dinv[i];
    const float4* a = (const float4*)(acc2 + (size_t)i * LD2);
    float4 t0 = a[0], t1 = a[1], t2 = a[2];
    float v[NCLS] = {t0.x, t0.y, t0.z, t0.w, t1.x, t1.y, t1.z, t1.w, t2.x, t2.y};
    float m = -1e30f;
#pragma unroll
    for (int j = 0; j < NCLS; ++j) {
        v[j] = v[j] * d + b2[j];
        m = fmaxf(m, v[j]);
    }
    float s = 0.f;
#pragma unroll
    for (int j = 0; j < NCLS; ++j) s += expf(v[j] - m);
    float l = logf(s);
    float* o = out + (size_t)i * NCLS;
#pragma unroll
    for (int j = 0; j < NCLS; ++j) o[j] = v[j] - m - l;
}

extern "C" void kernel_launch(void* const* d_in, const int* in_sizes, int n_in,
                              void* d_out, int out_size, void* d_ws, size_t ws_size,
                              hipStream_t stream) {
    const float* x  = (const float*)d_in[0];
    const int*   ei = (const int*)d_in[1];
    const float* W1 = (const float*)d_in[2];
    const float* b1 = (const float*)d_in[3];
    const float* W2 = (const float*)d_in[4];
    const float* b2 = (const float*)d_in[5];
    float* out = (float*)d_out;

    const int n = in_sizes[0] / F_IN;   // 200000
    const int E = in_sizes[1] / 2;      // 3200000
    const int* row = ei;
    const int* col = ei + E;

    float* ws   = (float*)d_ws;
    float* dinv = ws;                       // n floats
    float* hs1  = ws + 200000;              // n*LD1
    float* acc1 = ws + 7400000;             // n*LD1
    float* hs2  = ws + 14600000;            // n*LD2
    float* acc2 = ws + 17000000;            // n*LD2

    const int B = 256;
    k_init_deg<<<(n + B - 1) / B, B, 0, stream>>>(dinv, n);
    k_count_deg<<<(E + B - 1) / B, B, 0, stream>>>(col, E, dinv);
    k_rsqrt<<<(n + B - 1) / B, B, 0, stream>>>(dinv, n);

    k_gemm1<<<(n + B - 1) / B, B, 0, stream>>>(x, W1, dinv, hs1, n);
    hipMemcpyAsync(acc1, hs1, (size_t)n * LD1 * sizeof(float), hipMemcpyDeviceToDevice, stream);
    k_scatter1<<<(E + B - 1) / B, B, 0, stream>>>(row, col, E, hs1, acc1);

    k_layer2<<<(n + B - 1) / B, B, 0, stream>>>(acc1, dinv, b1, W2, hs2, n);
    hipMemcpyAsync(acc2, hs2, (size_t)n * LD2 * sizeof(float), hipMemcpyDeviceToDevice, stream);
    k_scatter2<<<(E + B - 1) / B, B, 0, stream>>>(row, col, E, hs2, acc2);

    k_out<<<(n + B - 1) / B, B, 0, stream>>>(acc2, dinv, b2, out, n);
}

// Round 2
// 776.000 us; speedup vs baseline: 9.6959x; 9.6959x over previous
//
#include <hip/hip_runtime.h>

#define NN    200000
#define F_IN  128
#define HID   35
#define NCLS  10
#define LD1   36   // padded row stride for 35-wide (144B, float4-aligned)
#define LD2   12   // padded row stride for 10-wide (48B)
#define SCAN_B 256

// ---------- degree / CSR build ----------

__global__ void k_count(const int* __restrict__ col, int E, int* __restrict__ cnt) {
    int e = blockIdx.x * blockDim.x + threadIdx.x;
    if (e < E) atomicAdd(&cnt[col[e]], 1);
}

__global__ void k_scan1(const int* __restrict__ cnt, int* __restrict__ offs,
                        int* __restrict__ bsum, int n) {
    __shared__ int sh[SCAN_B];
    int t = threadIdx.x;
    int i = blockIdx.x * SCAN_B + t;
    int v = (i < n) ? cnt[i] : 0;
    sh[t] = v;
    __syncthreads();
    for (int d = 1; d < SCAN_B; d <<= 1) {
        int add = (t >= d) ? sh[t - d] : 0;
        __syncthreads();
        sh[t] += add;
        __syncthreads();
    }
    if (i < n) offs[i] = sh[t] - v;          // exclusive prefix within block
    if (t == SCAN_B - 1) bsum[blockIdx.x] = sh[t];
}

__global__ void k_scan2(int* __restrict__ bsum, int nb) {
    __shared__ int sh[1024];
    int t = threadIdx.x;
    int v = (t < nb) ? bsum[t] : 0;
    sh[t] = v;
    __syncthreads();
    for (int d = 1; d < 1024; d <<= 1) {
        int add = (t >= d) ? sh[t - d] : 0;
        __syncthreads();
        sh[t] += add;
        __syncthreads();
    }
    if (t < nb) bsum[t] = sh[t] - v;         // exclusive block offsets
}

__global__ void k_scan3(int* __restrict__ offs, const int* __restrict__ bsum, int n, int E) {
    int i = blockIdx.x * blockDim.x + threadIdx.x;
    if (i < n) offs[i] += bsum[blockIdx.x];
    if (i == 0) offs[n] = E;
}

__global__ void k_dinv(const int* __restrict__ cnt, float* __restrict__ dinv, int n) {
    int i = blockIdx.x * blockDim.x + threadIdx.x;
    if (i < n) dinv[i] = rsqrtf((float)(cnt[i] + 1));   // +1 self loop, always > 0
}

__global__ void k_fill(const int* __restrict__ row, const int* __restrict__ col, int E,
                       int* __restrict__ cursor, int* __restrict__ srow) {
    int e = blockIdx.x * blockDim.x + threadIdx.x;
    if (e >= E) return;
    int pos = atomicAdd(&cursor[col[e]], 1);
    srow[pos] = row[e];
}

// ---------- layer 1 ----------

// hs1[i][j] = dinv[i] * sum_k x[i][k] * W1[k][j]
__global__ void k_gemm1(const float* __restrict__ x, const float* __restrict__ W1,
                        const float* __restrict__ dinv, float* __restrict__ hs1, int n) {
    int i = blockIdx.x * blockDim.x + threadIdx.x;
    if (i >= n) return;
    float acc[HID];
#pragma unroll
    for (int j = 0; j < HID; ++j) acc[j] = 0.f;
    const float4* xr = (const float4*)(x + (size_t)i * F_IN);
    for (int k4 = 0; k4 < F_IN / 4; ++k4) {
        float4 xv = xr[k4];
        const float* w = W1 + (size_t)(k4 * 4) * HID;   // uniform -> scalar loads
#pragma unroll
        for (int j = 0; j < HID; ++j)
            acc[j] += xv.x * w[j] + xv.y * w[HID + j] + xv.z * w[2 * HID + j] + xv.w * w[3 * HID + j];
    }
    float d = dinv[i];
    float* o = hs1 + (size_t)i * LD1;
#pragma unroll
    for (int j = 0; j < HID; ++j) o[j] = acc[j] * d;
}

// acc1[i] = hs1[i] + sum_{e: col=i} hs1[srow[e]]   (one wave per node, lane = feature)
__global__ void k_agg1(const int* __restrict__ offs, const int* __restrict__ srow,
                       const float* __restrict__ hs1, float* __restrict__ acc1, int n) {
    int wid = (blockIdx.x * blockDim.x + threadIdx.x) >> 6;
    int lane = threadIdx.x & 63;
    if (wid >= n) return;
    int beg = offs[wid], end = offs[wid + 1];
    bool act = lane < HID;
    float acc = 0.f;
    if (act) acc = hs1[(size_t)wid * LD1 + lane];        // self loop
    int j = beg;
    for (; j + 1 < end; j += 2) {
        int r0 = srow[j], r1 = srow[j + 1];
        float a0 = 0.f, a1 = 0.f;
        if (act) {
            a0 = hs1[(size_t)r0 * LD1 + lane];
            a1 = hs1[(size_t)r1 * LD1 + lane];
        }
        acc += a0 + a1;
    }
    if (j < end) {
        int r = srow[j];
        if (act) acc += hs1[(size_t)r * LD1 + lane];
    }
    if (act) acc1[(size_t)wid * LD1 + lane] = acc;
}

// ---------- layer 2 ----------

// h = relu(acc1*dinv + b1); hs2 = (h @ W2) * dinv
__global__ void k_layer2(const float* __restrict__ acc1, const float* __restrict__ dinv,
                         const float* __restrict__ b1, const float* __restrict__ W2,
                         float* __restrict__ hs2, int n) {
    int i = blockIdx.x * blockDim.x + threadIdx.x;
    if (i >= n) return;
    float d = dinv[i];
    const float4* a = (const float4*)(acc1 + (size_t)i * LD1);
    float4 t[9];
#pragma unroll
    for (int q = 0; q < 9; ++q) t[q] = a[q];
    const float* tf = (const float*)t;
    float h[HID];
#pragma unroll
    for (int k = 0; k < HID; ++k) {
        float v = tf[k] * d + b1[k];
        h[k] = v > 0.f ? v : 0.f;
    }
    float o[NCLS];
#pragma unroll
    for (int j = 0; j < NCLS; ++j) o[j] = 0.f;
#pragma unroll
    for (int k = 0; k < HID; ++k) {
#pragma unroll
        for (int j = 0; j < NCLS; ++j) o[j] += h[k] * W2[k * NCLS + j];
    }
    float* dst = hs2 + (size_t)i * LD2;
#pragma unroll
    for (int j = 0; j < NCLS; ++j) dst[j] = o[j] * d;
}

// acc2[i] = hs2[i] + sum_{e: col=i} hs2[srow[e]]  (wave per node, 4 edges via 16-lane subgroups)
__global__ void k_agg2(const int* __restrict__ offs, const int* __restrict__ srow,
                       const float* __restrict__ hs2, float* __restrict__ acc2, int n) {
    int wid = (blockIdx.x * blockDim.x + threadIdx.x) >> 6;
    int lane = threadIdx.x & 63;
    if (wid >= n) return;
    int sub = lane >> 4;          // 0..3
    int f = lane & 15;            // feature slot, active f < 12
    bool act = f < LD2;
    int beg = offs[wid], end = offs[wid + 1];
    float acc = 0.f;
    if (lane < LD2) acc = hs2[(size_t)wid * LD2 + lane];   // self loop (sub 0 only)
    for (int j = beg + sub; j < end; j += 4) {
        int r = srow[j];
        if (act) acc += hs2[(size_t)r * LD2 + f];
    }
    acc += __shfl_down(acc, 32);
    acc += __shfl_down(acc, 16);
    if (lane < LD2) acc2[(size_t)wid * LD2 + lane] = acc;
}

// out = log_softmax(acc2*dinv + b2)
__global__ void k_out(const float* __restrict__ acc2, const float* __restrict__ dinv,
                      const float* __restrict__ b2, float* __restrict__ out, int n) {
    int i = blockIdx.x * blockDim.x + threadIdx.x;
    if (i >= n) return;
    float d = dinv[i];
    const float4* a = (const float4*)(acc2 + (size_t)i * LD2);
    float4 t0 = a[0], t1 = a[1], t2 = a[2];
    float v[NCLS] = {t0.x, t0.y, t0.z, t0.w, t1.x, t1.y, t1.z, t1.w, t2.x, t2.y};
    float m = -1e30f;
#pragma unroll
    for (int j = 0; j < NCLS; ++j) {
        v[j] = v[j] * d + b2[j];
        m = fmaxf(m, v[j]);
    }
    float s = 0.f;
#pragma unroll
    for (int j = 0; j < NCLS; ++j) s += expf(v[j] - m);
    float l = logf(s);
    float* o = out + (size_t)i * NCLS;
#pragma unroll
    for (int j = 0; j < NCLS; ++j) o[j] = v[j] - m - l;
}

extern "C" void kernel_launch(void* const* d_in, const int* in_sizes, int n_in,
                              void* d_out, int out_size, void* d_ws, size_t ws_size,
                              hipStream_t stream) {
    const float* x  = (const float*)d_in[0];
    const int*   ei = (const int*)d_in[1];
    const float* W1 = (const float*)d_in[2];
    const float* b1 = (const float*)d_in[3];
    const float* W2 = (const float*)d_in[4];
    const float* b2 = (const float*)d_in[5];
    float* out = (float*)d_out;

    const int n = in_sizes[0] / F_IN;   // 200000
    const int E = in_sizes[1] / 2;      // 3200000
    const int* row = ei;
    const int* col = ei + E;

    // workspace layout (4B words), 16B-aligned float regions; total 73.6 MB
    int*   cnt    = (int*)d_ws;                   // [200000]
    int*   offs   = cnt + 200000;                 // [200004] (n+1 used)
    int*   cursor = cnt + 400004;                 // [200000]
    int*   bsum   = cnt + 600004;                 // [1024]
    int*   srow   = cnt + 601028;                 // [3200000]
    float* dinv   = (float*)(cnt + 3801028);      // [200000]
    float* hs1    = (float*)(cnt + 4001028);      // [7200000]
    float* acc1   = (float*)(cnt + 11201028);     // [7200000]
    float* hs2    = hs1;                          // alias: hs1 dead after agg1
    float* acc2   = hs1 + 2400000;                // alias

    const int B = 256;
    const int nb = (n + SCAN_B - 1) / SCAN_B;     // 782 blocks

    hipMemsetAsync(cnt, 0, (size_t)n * sizeof(int), stream);
    k_count<<<(E + B - 1) / B, B, 0, stream>>>(col, E, cnt);
    k_scan1<<<nb, SCAN_B, 0, stream>>>(cnt, offs, bsum, n);
    k_scan2<<<1, 1024, 0, stream>>>(bsum, nb);
    k_scan3<<<nb, SCAN_B, 0, stream>>>(offs, bsum, n, E);
    k_dinv<<<(n + B - 1) / B, B, 0, stream>>>(cnt, dinv, n);
    hipMemcpyAsync(cursor, offs, (size_t)n * sizeof(int), hipMemcpyDeviceToDevice, stream);
    k_fill<<<(E + B - 1) / B, B, 0, stream>>>(row, col, E, cursor, srow);

    k_gemm1<<<(n + B - 1) / B, B, 0, stream>>>(x, W1, dinv, hs1, n);
    k_agg1<<<(n * 64 + B - 1) / B, B, 0, stream>>>(offs, srow, hs1, acc1, n);
    k_layer2<<<(n + B - 1) / B, B, 0, stream>>>(acc1, dinv, b1, W2, hs2, n);
    k_agg2<<<(n * 64 + B - 1) / B, B, 0, stream>>>(offs, srow, hs2, acc2, n);
    k_out<<<(n + B - 1) / B, B, 0, stream>>>(acc2, dinv, b2, out, n);
}